// Round 11
// baseline (837.343 us; speedup 1.0000x reference)
//
#include <hip/hip_runtime.h>
#include <hip/hip_fp16.h>
#include <hip/hip_cooperative_groups.h>

namespace cg = cooperative_groups;

#define ALPHA 0.5f

typedef short short8v __attribute__((ext_vector_type(8)));
typedef float f32x4 __attribute__((ext_vector_type(4)));

__device__ __forceinline__ unsigned short f2bf(float f) {
  union { float f; unsigned u; } v; v.f = f;
  unsigned r = v.u + 0x7FFFu + ((v.u >> 16) & 1u);   // RNE
  return (unsigned short)(r >> 16);
}
__device__ __forceinline__ float bf2f(unsigned short u) {
  union { unsigned u; float f; } v; v.u = ((unsigned)u) << 16;
  return v.f;
}
__device__ __forceinline__ float unpack_w(unsigned p) {
  return __half2float(__ushort_as_half((unsigned short)((p & 0x7FFFu) << 1)));
}

// ================= fused cooperative kernel: prep + CSR build =================
// Grid: 1536 blocks x 256 threads (6 blocks/CU, 24 waves/CU; capacity limit is 8).
// Phase 0: W transpose (blocks 0..255) + deg zero + A->bf16 cvt (all blocks)
// Phase 1: degree histogram        Phase 2a/2b: two-level exclusive scan
// Phase 3: reindex edges into CSR slots (packed 4B edge words)
__global__ __launch_bounds__(256) void fused_csr(
    const int* __restrict__ src, const int* __restrict__ dst,
    const float* __restrict__ wgt,
    const float* __restrict__ W, unsigned short* __restrict__ Wt,
    const float* __restrict__ A, unsigned short* __restrict__ Ab,
    int* __restrict__ deg, int* __restrict__ excl,
    int* __restrict__ row_ptr, int* __restrict__ cursor,
    int* __restrict__ partial,
    unsigned* __restrict__ edges,
    int N, int E, int n8, int NB) {
  cg::grid_group grid = cg::this_grid();
  const int tid = threadIdx.x;
  const int bid = blockIdx.x;
  const int gid = bid * 256 + tid;
  const int gstride = gridDim.x * 256;

  __shared__ float tile[16][17];
  __shared__ int wsum[4];
  __shared__ int s_off;

  // ---- phase 0: W transpose (blocks 0..255 only) + deg zero + A cvt ----
  {
    if (bid < 256) {
      const int kb = (bid & 15) * 16, nb = (bid >> 4) * 16;
      const int tx = tid & 15, ty = tid >> 4;
      tile[ty][tx] = W[(kb + ty) * 256 + nb + tx];
      __syncthreads();
      Wt[(nb + ty) * 256 + kb + tx] = f2bf(tile[tx][ty]);
    }
    if (gid < N) deg[gid] = 0;

    for (int i = gid; i < n8; i += gstride) {
      float4 a = *reinterpret_cast<const float4*>(&A[i * 8]);
      float4 b = *reinterpret_cast<const float4*>(&A[i * 8 + 4]);
      unsigned short o[8] = {f2bf(a.x), f2bf(a.y), f2bf(a.z), f2bf(a.w),
                             f2bf(b.x), f2bf(b.y), f2bf(b.z), f2bf(b.w)};
      *reinterpret_cast<short8v*>(&Ab[i * 8]) = *reinterpret_cast<short8v*>(o);
    }
  }
  grid.sync();

  // ---- phase 1: histogram (4 edges/thread/iter) ----
  {
    const int E4 = E & ~3;
    for (int i = gid * 4; i < E4; i += gstride * 4) {
      int4 d = *reinterpret_cast<const int4*>(&dst[i]);
      atomicAdd(&deg[d.x], 1); atomicAdd(&deg[d.y], 1);
      atomicAdd(&deg[d.z], 1); atomicAdd(&deg[d.w], 1);
    }
    if (gid < (E - E4)) atomicAdd(&deg[dst[E4 + gid]], 1);
  }
  grid.sync();

  // ---- phase 2a: per-1024-chunk exclusive scan (blocks 0..NB-1) ----
  if (bid < NB) {
    const int base = bid * 1024 + tid * 4;
    int4 v = make_int4(0, 0, 0, 0);
    if (base + 3 < N) v = *reinterpret_cast<const int4*>(&deg[base]);
    else {
      if (base + 0 < N) v.x = deg[base + 0];
      if (base + 1 < N) v.y = deg[base + 1];
      if (base + 2 < N) v.z = deg[base + 2];
    }
    const int s = v.x + v.y + v.z + v.w;
    const int lane = tid & 63, wid = tid >> 6;
    int ps = s;
    #pragma unroll
    for (int off = 1; off < 64; off <<= 1) {
      int t = __shfl_up(ps, off, 64);
      if (lane >= off) ps += t;
    }
    if (lane == 63) wsum[wid] = ps;
    __syncthreads();
    int woff = 0;
    #pragma unroll
    for (int w2 = 0; w2 < 4; ++w2) woff += (w2 < wid) ? wsum[w2] : 0;
    const int texcl = woff + ps - s;
    int4 e = make_int4(texcl, texcl + v.x, texcl + v.x + v.y, texcl + v.x + v.y + v.z);
    if (base + 3 < N) *reinterpret_cast<int4*>(&excl[base]) = e;
    else {
      if (base + 0 < N) excl[base + 0] = e.x;
      if (base + 1 < N) excl[base + 1] = e.y;
      if (base + 2 < N) excl[base + 2] = e.z;
    }
    if (tid == 255) partial[bid] = woff + ps;
  }
  grid.sync();

  // ---- phase 2b: apply block offsets (blocks 0..NB-1) ----
  if (bid < NB) {
    if (tid < 64) {
      int v = (tid < NB && tid < bid) ? partial[tid] : 0;
      #pragma unroll
      for (int off = 1; off < 64; off <<= 1) v += __shfl_xor(v, off, 64);
      if (tid == 0) s_off = v;
    }
    if (bid == 0 && tid == 0) row_ptr[N] = E;   // sentinel
    __syncthreads();
    const int off = s_off;
    const int base = bid * 1024 + tid * 4;
    if (base + 3 < N) {
      int4 v = *reinterpret_cast<const int4*>(&excl[base]);
      v.x += off; v.y += off; v.z += off; v.w += off;
      *reinterpret_cast<int4*>(&row_ptr[base]) = v;
      *reinterpret_cast<int4*>(&cursor[base]) = v;
    } else {
      for (int j = 0; j < 4; ++j)
        if (base + j < N) { int v = excl[base + j] + off; row_ptr[base + j] = v; cursor[base + j] = v; }
    }
  }
  grid.sync();

  // ---- phase 3: reindex (4 edges/thread/iter) ----
  {
    const int E4 = E & ~3;
    for (int i = gid * 4; i < E4; i += gstride * 4) {
      int4 sv = *reinterpret_cast<const int4*>(&src[i]);
      int4 dv = *reinterpret_cast<const int4*>(&dst[i]);
      float4 wv = *reinterpret_cast<const float4*>(&wgt[i]);
      int s_[4] = {sv.x, sv.y, sv.z, sv.w};
      int d_[4] = {dv.x, dv.y, dv.z, dv.w};
      float w_[4] = {wv.x, wv.y, wv.z, wv.w};
      #pragma unroll
      for (int j = 0; j < 4; ++j) {
        int slot = atomicAdd(&cursor[d_[j]], 1);
        unsigned hb = __half_as_ushort(__float2half(w_[j] * ALPHA));
        edges[slot] = ((unsigned)s_[j] << 15) | (hb >> 1);
      }
    }
    if (gid < (E - E4)) {
      int i = E4 + gid;
      int slot = atomicAdd(&cursor[dst[i]], 1);
      unsigned hb = __half_as_ushort(__float2half(wgt[i] * ALPHA));
      edges[slot] = ((unsigned)src[i] << 15) | (hb >> 1);
    }
  }
}

// ---------------- GEMM: support(bf16) = Ab @ W via MFMA ----------------
// 64x256 tile, 4 waves, wave w = rows 0..63 x cols [w*64, w*64+64) -> acc[4][4].
// LDS/buf: A 4x1KB @0, B 16x1KB @4096 (frag order). Double-buffered = 40KB.
__global__ __launch_bounds__(256) void gemm_mfma(
    const unsigned short* __restrict__ Ab, const unsigned short* __restrict__ Wt,
    unsigned short* __restrict__ C, int M) {
  __shared__ char smem[2][20480];
  const int tid = threadIdx.x;
  const int lane = tid & 63;
  const int w = tid >> 6;
  const int row0 = blockIdx.x * 64;

  f32x4 acc[4][4];
  #pragma unroll
  for (int m = 0; m < 4; ++m)
    #pragma unroll
    for (int n = 0; n < 4; ++n) acc[m][n] = (f32x4){0.f, 0.f, 0.f, 0.f};

  int r = row0 + w * 16 + (lane & 15);
  const int arow = (r < M) ? r : (M - 1);
  const int kh = (lane >> 4) * 8;

  int cur = 0;
  {
    const unsigned short* ga = Ab + (size_t)arow * 256 + kh;
    __builtin_amdgcn_global_load_lds(
        (const __attribute__((address_space(1))) void*)ga,
        (__attribute__((address_space(3))) void*)(&smem[0][w * 1024]),
        16, 0, 0);
    #pragma unroll
    for (int i = 0; i < 4; ++i) {
      int s = w * 4 + i;
      const unsigned short* g = Wt + (size_t)(s * 16 + (lane & 15)) * 256 + kh;
      __builtin_amdgcn_global_load_lds(
          (const __attribute__((address_space(1))) void*)g,
          (__attribute__((address_space(3))) void*)(&smem[0][4096 + s * 1024]),
          16, 0, 0);
    }
    __syncthreads();
  }

  #pragma unroll
  for (int t = 0; t < 8; ++t) {
    const bool pf = (t < 7);
    if (pf) {
      const int k0 = (t + 1) * 32;
      const unsigned short* ga = Ab + (size_t)arow * 256 + k0 + kh;
      __builtin_amdgcn_global_load_lds(
          (const __attribute__((address_space(1))) void*)ga,
          (__attribute__((address_space(3))) void*)(&smem[cur ^ 1][w * 1024]),
          16, 0, 0);
      #pragma unroll
      for (int i = 0; i < 4; ++i) {
        int s = w * 4 + i;
        const unsigned short* g = Wt + (size_t)(s * 16 + (lane & 15)) * 256 + k0 + kh;
        __builtin_amdgcn_global_load_lds(
            (const __attribute__((address_space(1))) void*)g,
            (__attribute__((address_space(3))) void*)(&smem[cur ^ 1][4096 + s * 1024]),
            16, 0, 0);
      }
    }
    short8v af[4], bfv[4];
    #pragma unroll
    for (int m = 0; m < 4; ++m)
      af[m] = *reinterpret_cast<const short8v*>(&smem[cur][m * 1024 + lane * 16]);
    #pragma unroll
    for (int n = 0; n < 4; ++n)
      bfv[n] = *reinterpret_cast<const short8v*>(&smem[cur][4096 + (w * 4 + n) * 1024 + lane * 16]);
    #pragma unroll
    for (int m = 0; m < 4; ++m)
      #pragma unroll
      for (int n = 0; n < 4; ++n)
        acc[m][n] = __builtin_amdgcn_mfma_f32_16x16x32_bf16(af[m], bfv[n], acc[m][n], 0, 0, 0);
    __syncthreads();
    cur ^= 1;
  }

  #pragma unroll
  for (int m = 0; m < 4; ++m) {
    #pragma unroll
    for (int n = 0; n < 4; ++n) {
      const int col = w * 64 + n * 16 + (lane & 15);
      #pragma unroll
      for (int r2 = 0; r2 < 4; ++r2) {
        const int row = row0 + m * 16 + (lane >> 4) * 4 + r2;
        if (row < M) C[(size_t)row * 256 + col] = f2bf(acc[m][n][r2]);
      }
    }
  }
}

// ---------------- aggregate (pull, bf16 support, full-row bursts), fused blend+relu ----------------
__global__ __launch_bounds__(256) void aggregate(
    const unsigned short* __restrict__ support,
    const int* __restrict__ row_ptr,
    const unsigned* __restrict__ edges,
    const float* __restrict__ init, float* __restrict__ out, int N) {
  int node = blockIdx.x * 4 + (threadIdx.x >> 6);
  if (node >= N) return;
  int lane = threadIdx.x & 63;
  int start = row_ptr[node];
  int cnt = row_ptr[node + 1] - start;

  float4 ini = *reinterpret_cast<const float4*>(&init[(size_t)node * 256 + lane * 4]);

  float4 acc = make_float4(0.f, 0.f, 0.f, 0.f);
  int e = 0;
  for (; e + 7 < cnt; e += 8) {  // 8 outstanding contiguous 512B gathers per wave
    unsigned p[8];
    #pragma unroll
    for (int j = 0; j < 8; ++j) p[j] = edges[start + e + j];
    ushort4 v[8];
    #pragma unroll
    for (int j = 0; j < 8; ++j)
      v[j] = *reinterpret_cast<const ushort4*>(&support[(size_t)(p[j] >> 15) * 256 + lane * 4]);
    #pragma unroll
    for (int j = 0; j < 8; ++j) {
      float wj = unpack_w(p[j]);
      acc.x += wj * bf2f(v[j].x);
      acc.y += wj * bf2f(v[j].y);
      acc.z += wj * bf2f(v[j].z);
      acc.w += wj * bf2f(v[j].w);
    }
  }
  for (; e < cnt; ++e) {
    unsigned p = edges[start + e];
    ushort4 v = *reinterpret_cast<const ushort4*>(&support[(size_t)(p >> 15) * 256 + lane * 4]);
    float wj = unpack_w(p);
    acc.x += wj * bf2f(v.x); acc.y += wj * bf2f(v.y);
    acc.z += wj * bf2f(v.z); acc.w += wj * bf2f(v.w);
  }
  float4 o;
  o.x = fmaxf(acc.x + (1.f - ALPHA) * ini.x, 0.f);
  o.y = fmaxf(acc.y + (1.f - ALPHA) * ini.y, 0.f);
  o.z = fmaxf(acc.z + (1.f - ALPHA) * ini.z, 0.f);
  o.w = fmaxf(acc.w + (1.f - ALPHA) * ini.w, 0.f);
  *reinterpret_cast<float4*>(&out[(size_t)node * 256 + lane * 4]) = o;
}

extern "C" void kernel_launch(void* const* d_in, const int* in_sizes, int n_in,
                              void* d_out, int out_size, void* d_ws, size_t ws_size,
                              hipStream_t stream) {
  const float* input   = (const float*)d_in[0];
  const int*   adj_src = (const int*)d_in[1];
  const int*   adj_dst = (const int*)d_in[2];
  const float* adj_w   = (const float*)d_in[3];
  const float* init_in = (const float*)d_in[4];
  const float* weight  = (const float*)d_in[5];
  float* out = (float*)d_out;

  const int N = in_sizes[0] / 256;  // 50000
  const int E = in_sizes[1];        // 800000

  char* ws = (char*)d_ws;
  unsigned short* support = (unsigned short*)ws; ws += (size_t)N * 256 * 2;  // 25.6 MB
  unsigned short* Ab      = (unsigned short*)ws; ws += (size_t)N * 256 * 2;  // 25.6 MB
  unsigned short* Wt      = (unsigned short*)ws; ws += 256 * 256 * 2;
  int* deg     = (int*)ws; ws += (size_t)N * 4;
  int* row_ptr = (int*)ws; ws += (size_t)(N + 1) * 4;
  int* cursor  = (int*)ws; ws += (size_t)N * 4;
  int* excl    = (int*)ws; ws += (size_t)N * 4;
  int* partial = (int*)ws; ws += 256;
  unsigned* edges = (unsigned*)ws; ws += (size_t)E * 4;

  const int NB = (N + 1023) / 1024;  // 49 (<= 64 required by phase 2b)
  int n8 = N * 256 / 8;

  // one cooperative dispatch: prep + histogram + scan + reindex
  // 1536 blocks = 6 blocks/CU (capacity 8 at VGPR=12/LDS=1.5KB) -> 24 waves/CU
  {
    void* args[] = {(void*)&adj_src, (void*)&adj_dst, (void*)&adj_w,
                    (void*)&weight, (void*)&Wt, (void*)&input, (void*)&Ab,
                    (void*)&deg, (void*)&excl, (void*)&row_ptr, (void*)&cursor,
                    (void*)&partial, (void*)&edges,
                    (void*)&N, (void*)&E, (void*)&n8, (void*)&NB};
    hipLaunchCooperativeKernel((const void*)fused_csr, dim3(1536), dim3(256),
                               args, 0, stream);
  }

  gemm_mfma<<<(N + 63) / 64, 256, 0, stream>>>(Ab, Wt, support, N);

  aggregate<<<(N + 3) / 4, 256, 0, stream>>>(support, row_ptr, edges, init_in, out, N);
}

// Round 12
// 173.235 us; speedup vs baseline: 4.8336x; 4.8336x over previous
//
#include <hip/hip_runtime.h>
#include <hip/hip_fp16.h>

#define ALPHA 0.5f

typedef short short8v __attribute__((ext_vector_type(8)));
typedef float f32x4 __attribute__((ext_vector_type(4)));

__device__ __forceinline__ unsigned short f2bf(float f) {
  union { float f; unsigned u; } v; v.f = f;
  unsigned r = v.u + 0x7FFFu + ((v.u >> 16) & 1u);   // RNE
  return (unsigned short)(r >> 16);
}
__device__ __forceinline__ float bf2f(unsigned short u) {
  union { unsigned u; float f; } v; v.u = ((unsigned)u) << 16;
  return v.f;
}
__device__ __forceinline__ float unpack_w(unsigned p) {
  return __half2float(__ushort_as_half((unsigned short)((p & 0x7FFFu) << 1)));
}

// ---------------- K0: W transpose (blocks 0..255) + deg zero (blocks 256+) ----------------
__global__ __launch_bounds__(256) void prep_small(
    const float* __restrict__ W, unsigned short* __restrict__ Wt,
    int* __restrict__ deg, int N) {
  const int tid = threadIdx.x;
  const int bid = blockIdx.x;
  if (bid < 256) {
    __shared__ float tile[16][17];
    const int kb = (bid & 15) * 16, nb = (bid >> 4) * 16;
    const int tx = tid & 15, ty = tid >> 4;
    tile[ty][tx] = W[(kb + ty) * 256 + nb + tx];
    __syncthreads();
    Wt[(nb + ty) * 256 + kb + tx] = f2bf(tile[tx][ty]);
  } else {
    const int i4 = (bid - 256) * 256 + tid;
    const int base = i4 * 4;
    if (base + 3 < N) *reinterpret_cast<int4*>(&deg[base]) = make_int4(0, 0, 0, 0);
    else for (int j = 0; j < 4; ++j) if (base + j < N) deg[base + j] = 0;
  }
}

// ================ K1: heterogeneous dispatch — gemm (blocks < GB) ∪ histogram ================
// gemm role: R5-proven 128x256 tile, 4 waves (wm=w>>1, wn=w&1), acc[4][8].
//   A fp32 reg-staged + cvt to LDS frag-order; B bf16 via global_load_lds width=16.
// histogram role: 4 edges/thread grid-stride atomics. Roles are independent (no sync).
__global__ __launch_bounds__(256) void gemm_hist(
    const float* __restrict__ A, const unsigned short* __restrict__ Wt,
    unsigned short* __restrict__ C, int M,
    const int* __restrict__ dst, int* __restrict__ deg, int E, int GB, int HB) {
  __shared__ char smem[2][24576];
  const int tid = threadIdx.x;
  const int bid = blockIdx.x;

  if (bid >= GB) {
    // ---- histogram role ----
    const int hgid = (bid - GB) * 256 + tid;
    const int hstride = HB * 256;
    const int E4 = E & ~3;
    for (int i = hgid * 4; i < E4; i += hstride * 4) {
      int4 d = *reinterpret_cast<const int4*>(&dst[i]);
      atomicAdd(&deg[d.x], 1); atomicAdd(&deg[d.y], 1);
      atomicAdd(&deg[d.z], 1); atomicAdd(&deg[d.w], 1);
    }
    if (hgid < (E - E4)) atomicAdd(&deg[dst[E4 + hgid]], 1);
    return;
  }

  // ---- gemm role ----
  const int lane = tid & 63;
  const int w = tid >> 6;
  const int wm = w >> 1, wn = w & 1;
  const int row0 = bid * 128;

  f32x4 acc[4][8];
  #pragma unroll
  for (int m = 0; m < 4; ++m)
    #pragma unroll
    for (int n = 0; n < 8; ++n) acc[m][n] = (f32x4){0.f, 0.f, 0.f, 0.f};

  const int aR = tid >> 1;
  const int aKs = (tid & 1) * 16;
  const int aRow = (row0 + aR < M) ? (row0 + aR) : (M - 1);
  const float* aP = A + (size_t)aRow * 256 + aKs;
  const int aWrOff = (aR >> 4) * 1024 + (aKs >> 3) * 256 + (aR & 15) * 16;

  int cur = 0;
  {
    float4 av[4];
    #pragma unroll
    for (int j = 0; j < 4; ++j) av[j] = *reinterpret_cast<const float4*>(aP + j * 4);
    #pragma unroll
    for (int i = 0; i < 4; ++i) {
      int s = w * 4 + i;
      const unsigned short* g = Wt + (size_t)(s * 16 + (lane & 15)) * 256 + (lane >> 4) * 8;
      __builtin_amdgcn_global_load_lds(
          (const __attribute__((address_space(1))) void*)g,
          (__attribute__((address_space(3))) void*)(&smem[0][8192 + s * 1024]),
          16, 0, 0);
    }
    unsigned short ab[16];
    #pragma unroll
    for (int j = 0; j < 4; ++j) {
      ab[j * 4 + 0] = f2bf(av[j].x); ab[j * 4 + 1] = f2bf(av[j].y);
      ab[j * 4 + 2] = f2bf(av[j].z); ab[j * 4 + 3] = f2bf(av[j].w);
    }
    *reinterpret_cast<short8v*>(&smem[0][aWrOff])       = *reinterpret_cast<short8v*>(&ab[0]);
    *reinterpret_cast<short8v*>(&smem[0][aWrOff + 256]) = *reinterpret_cast<short8v*>(&ab[8]);
    __syncthreads();
  }

  #pragma unroll
  for (int t = 0; t < 8; ++t) {
    float4 av[4];
    const bool pf = (t < 7);
    if (pf) {
      const int k0 = (t + 1) * 32;
      #pragma unroll
      for (int j = 0; j < 4; ++j) av[j] = *reinterpret_cast<const float4*>(aP + k0 + j * 4);
      #pragma unroll
      for (int i = 0; i < 4; ++i) {
        int s = w * 4 + i;
        const unsigned short* g = Wt + (size_t)(s * 16 + (lane & 15)) * 256 + k0 + (lane >> 4) * 8;
        __builtin_amdgcn_global_load_lds(
            (const __attribute__((address_space(1))) void*)g,
            (__attribute__((address_space(3))) void*)(&smem[cur ^ 1][8192 + s * 1024]),
            16, 0, 0);
      }
    }
    short8v af[4], bfv[8];
    #pragma unroll
    for (int m = 0; m < 4; ++m)
      af[m] = *reinterpret_cast<const short8v*>(&smem[cur][(wm * 4 + m) * 1024 + lane * 16]);
    #pragma unroll
    for (int n = 0; n < 8; ++n)
      bfv[n] = *reinterpret_cast<const short8v*>(&smem[cur][8192 + (wn * 8 + n) * 1024 + lane * 16]);
    #pragma unroll
    for (int m = 0; m < 4; ++m)
      #pragma unroll
      for (int n = 0; n < 8; ++n)
        acc[m][n] = __builtin_amdgcn_mfma_f32_16x16x32_bf16(af[m], bfv[n], acc[m][n], 0, 0, 0);
    if (pf) {
      unsigned short ab[16];
      #pragma unroll
      for (int j = 0; j < 4; ++j) {
        ab[j * 4 + 0] = f2bf(av[j].x); ab[j * 4 + 1] = f2bf(av[j].y);
        ab[j * 4 + 2] = f2bf(av[j].z); ab[j * 4 + 3] = f2bf(av[j].w);
      }
      *reinterpret_cast<short8v*>(&smem[cur ^ 1][aWrOff])       = *reinterpret_cast<short8v*>(&ab[0]);
      *reinterpret_cast<short8v*>(&smem[cur ^ 1][aWrOff + 256]) = *reinterpret_cast<short8v*>(&ab[8]);
    }
    __syncthreads();
    cur ^= 1;
  }

  #pragma unroll
  for (int m = 0; m < 4; ++m) {
    #pragma unroll
    for (int n = 0; n < 8; ++n) {
      const int col = wn * 128 + n * 16 + (lane & 15);
      #pragma unroll
      for (int r = 0; r < 4; ++r) {
        const int row = row0 + wm * 64 + m * 16 + (lane >> 4) * 4 + r;
        if (row < M) C[(size_t)row * 256 + col] = f2bf(acc[m][n][r]);
      }
    }
  }
}

// ---------------- CSR scan ----------------
__global__ __launch_bounds__(256) void scan_pass1(const int* __restrict__ deg,
                                                  int* __restrict__ excl,
                                                  int* __restrict__ partial, int N) {
  const int tid = threadIdx.x;
  const int base = blockIdx.x * 1024 + tid * 4;
  int4 v = make_int4(0, 0, 0, 0);
  if (base + 3 < N) v = *reinterpret_cast<const int4*>(&deg[base]);
  else {
    if (base + 0 < N) v.x = deg[base + 0];
    if (base + 1 < N) v.y = deg[base + 1];
    if (base + 2 < N) v.z = deg[base + 2];
  }
  const int s = v.x + v.y + v.z + v.w;
  const int lane = tid & 63, wid = tid >> 6;
  int ps = s;
  #pragma unroll
  for (int off = 1; off < 64; off <<= 1) {
    int t = __shfl_up(ps, off, 64);
    if (lane >= off) ps += t;
  }
  __shared__ int wsum[4];
  if (lane == 63) wsum[wid] = ps;
  __syncthreads();
  int woff = 0;
  #pragma unroll
  for (int w2 = 0; w2 < 4; ++w2) woff += (w2 < wid) ? wsum[w2] : 0;
  const int texcl = woff + ps - s;
  int4 e = make_int4(texcl, texcl + v.x, texcl + v.x + v.y, texcl + v.x + v.y + v.z);
  if (base + 3 < N) *reinterpret_cast<int4*>(&excl[base]) = e;
  else {
    if (base + 0 < N) excl[base + 0] = e.x;
    if (base + 1 < N) excl[base + 1] = e.y;
    if (base + 2 < N) excl[base + 2] = e.z;
  }
  if (tid == 255) partial[blockIdx.x] = woff + ps;
}

__global__ __launch_bounds__(256) void scan_pass2(const int* __restrict__ excl,
                                                  const int* __restrict__ partial,
                                                  int* __restrict__ row_ptr,
                                                  int* __restrict__ cursor,
                                                  int N, int NB, int E) {
  __shared__ int s_off;
  const int tid = threadIdx.x;
  if (tid < 64) {
    int v = (tid < NB && tid < (int)blockIdx.x) ? partial[tid] : 0;
    #pragma unroll
    for (int off = 1; off < 64; off <<= 1) v += __shfl_xor(v, off, 64);
    if (tid == 0) s_off = v;
  }
  if (blockIdx.x == 0 && tid == 0) row_ptr[N] = E;   // sentinel
  __syncthreads();
  const int off = s_off;
  const int base = blockIdx.x * 1024 + tid * 4;
  if (base + 3 < N) {
    int4 v = *reinterpret_cast<const int4*>(&excl[base]);
    v.x += off; v.y += off; v.z += off; v.w += off;
    *reinterpret_cast<int4*>(&row_ptr[base]) = v;
    *reinterpret_cast<int4*>(&cursor[base]) = v;
  } else {
    for (int j = 0; j < 4; ++j)
      if (base + j < N) { int v = excl[base + j] + off; row_ptr[base + j] = v; cursor[base + j] = v; }
  }
}

// edge word: src (17 bits) << 15 | fp16(w*alpha) >> 1 (15 bits; w*alpha in [0,0.5])
__global__ __launch_bounds__(256) void reindex_edges(
    const int* __restrict__ src, const int* __restrict__ dst,
    const float* __restrict__ w, int* __restrict__ cursor,
    unsigned* __restrict__ edges, int E) {
  int i = (blockIdx.x * blockDim.x + threadIdx.x) * 4;
  if (i + 3 < E) {
    int4 sv = *reinterpret_cast<const int4*>(&src[i]);
    int4 dv = *reinterpret_cast<const int4*>(&dst[i]);
    float4 wv = *reinterpret_cast<const float4*>(&w[i]);
    int s_[4] = {sv.x, sv.y, sv.z, sv.w};
    int d_[4] = {dv.x, dv.y, dv.z, dv.w};
    float w_[4] = {wv.x, wv.y, wv.z, wv.w};
    #pragma unroll
    for (int j = 0; j < 4; ++j) {
      int slot = atomicAdd(&cursor[d_[j]], 1);
      unsigned hb = __half_as_ushort(__float2half(w_[j] * ALPHA));
      edges[slot] = ((unsigned)s_[j] << 15) | (hb >> 1);
    }
  } else {
    for (; i < E; ++i) {
      int slot = atomicAdd(&cursor[dst[i]], 1);
      unsigned hb = __half_as_ushort(__float2half(w[i] * ALPHA));
      edges[slot] = ((unsigned)src[i] << 15) | (hb >> 1);
    }
  }
}

// ---------------- aggregate (pull, bf16 support, full-row bursts), fused blend+relu ----------------
__global__ __launch_bounds__(256) void aggregate(
    const unsigned short* __restrict__ support,
    const int* __restrict__ row_ptr,
    const unsigned* __restrict__ edges,
    const float* __restrict__ init, float* __restrict__ out, int N) {
  int node = blockIdx.x * 4 + (threadIdx.x >> 6);
  if (node >= N) return;
  int lane = threadIdx.x & 63;
  int start = row_ptr[node];
  int cnt = row_ptr[node + 1] - start;

  float4 ini = *reinterpret_cast<const float4*>(&init[(size_t)node * 256 + lane * 4]);

  float4 acc = make_float4(0.f, 0.f, 0.f, 0.f);
  int e = 0;
  for (; e + 7 < cnt; e += 8) {  // 8 outstanding contiguous 512B gathers per wave
    unsigned p[8];
    #pragma unroll
    for (int j = 0; j < 8; ++j) p[j] = edges[start + e + j];
    ushort4 v[8];
    #pragma unroll
    for (int j = 0; j < 8; ++j)
      v[j] = *reinterpret_cast<const ushort4*>(&support[(size_t)(p[j] >> 15) * 256 + lane * 4]);
    #pragma unroll
    for (int j = 0; j < 8; ++j) {
      float wj = unpack_w(p[j]);
      acc.x += wj * bf2f(v[j].x);
      acc.y += wj * bf2f(v[j].y);
      acc.z += wj * bf2f(v[j].z);
      acc.w += wj * bf2f(v[j].w);
    }
  }
  for (; e < cnt; ++e) {
    unsigned p = edges[start + e];
    ushort4 v = *reinterpret_cast<const ushort4*>(&support[(size_t)(p >> 15) * 256 + lane * 4]);
    float wj = unpack_w(p);
    acc.x += wj * bf2f(v.x); acc.y += wj * bf2f(v.y);
    acc.z += wj * bf2f(v.z); acc.w += wj * bf2f(v.w);
  }
  float4 o;
  o.x = fmaxf(acc.x + (1.f - ALPHA) * ini.x, 0.f);
  o.y = fmaxf(acc.y + (1.f - ALPHA) * ini.y, 0.f);
  o.z = fmaxf(acc.z + (1.f - ALPHA) * ini.z, 0.f);
  o.w = fmaxf(acc.w + (1.f - ALPHA) * ini.w, 0.f);
  *reinterpret_cast<float4*>(&out[(size_t)node * 256 + lane * 4]) = o;
}

extern "C" void kernel_launch(void* const* d_in, const int* in_sizes, int n_in,
                              void* d_out, int out_size, void* d_ws, size_t ws_size,
                              hipStream_t stream) {
  const float* input   = (const float*)d_in[0];
  const int*   adj_src = (const int*)d_in[1];
  const int*   adj_dst = (const int*)d_in[2];
  const float* adj_w   = (const float*)d_in[3];
  const float* init_in = (const float*)d_in[4];
  const float* weight  = (const float*)d_in[5];
  float* out = (float*)d_out;

  const int N = in_sizes[0] / 256;  // 50000
  const int E = in_sizes[1];        // 800000

  char* ws = (char*)d_ws;
  unsigned short* support = (unsigned short*)ws; ws += (size_t)N * 256 * 2;  // 25.6 MB
  unsigned short* Wt      = (unsigned short*)ws; ws += 256 * 256 * 2;
  int* deg     = (int*)ws; ws += (size_t)N * 4;
  int* row_ptr = (int*)ws; ws += (size_t)(N + 1) * 4;
  int* cursor  = (int*)ws; ws += (size_t)N * 4;
  int* excl    = (int*)ws; ws += (size_t)N * 4;
  int* partial = (int*)ws; ws += 256;
  unsigned* edges = (unsigned*)ws; ws += (size_t)E * 4;

  const int NB = (N + 1023) / 1024;         // 49 (<= 64 required by scan_pass2)
  const int GB = (N + 127) / 128;           // 391 gemm blocks
  const int HB = 800;                       // histogram blocks

  // K0: W transpose + deg zero
  prep_small<<<256 + (N / 4 + 255) / 256, 256, 0, stream>>>(weight, Wt, deg, N);

  // K1: gemm ∪ histogram (independent roles, one dispatch)
  gemm_hist<<<GB + HB, 256, 0, stream>>>(input, Wt, support, N,
                                         adj_dst, deg, E, GB, HB);

  scan_pass1<<<NB, 256, 0, stream>>>(deg, excl, partial, N);
  scan_pass2<<<NB, 256, 0, stream>>>(excl, partial, row_ptr, cursor, N, NB, E);
  reindex_edges<<<(E / 4 + 255) / 256, 256, 0, stream>>>(adj_src, adj_dst, adj_w, cursor, edges, E);

  aggregate<<<(N + 3) / 4, 256, 0, stream>>>(support, row_ptr, edges, init_in, out, N);
}